// Round 3
// baseline (737.356 us; speedup 1.0000x reference)
//
#include <hip/hip_runtime.h>
#include <hip/hip_bf16.h>
#include <math.h>

#define THETA 0.7f

typedef short short8 __attribute__((ext_vector_type(8)));
typedef float floatx4 __attribute__((ext_vector_type(4)));

__device__ __forceinline__ unsigned short f2bu(float f) {
    return __builtin_bit_cast(unsigned short, __float2bfloat16(f));
}
__device__ __forceinline__ float b2f(unsigned short u) {
    unsigned v = ((unsigned)u) << 16;
    return __builtin_bit_cast(float, v);
}
__device__ __forceinline__ float wsum64(float v) {
    v += __shfl_xor(v, 32); v += __shfl_xor(v, 16); v += __shfl_xor(v, 8);
    v += __shfl_xor(v, 4);  v += __shfl_xor(v, 2);  v += __shfl_xor(v, 1);
    return v;
}

// Fused prep + stats, one launch (independent work, disjoint block ranges).
// Blocks 0..511   : per-(b,c)-plane stats (closed-form GAP inputs).
//   stats[plane*10 + {0:T,1:R0,2:R255,3:C0,4:C255,5:x00,6:x0_255,
//                     7:x255_0,8:x255_255,9:sum|x(r-1)-x(r+1)|}]
// Blocks 512..559 : Bw[2 chunks][64 n][384 k] bf16 fused weights.
// Blocks 560..599 : Wt[(c*9+tap)*64+o] = Wc[o*576+c*9+tap] (coalesced-read
//                   transpose) and Wet[c*64+o] = We[o*64+c].
__global__ __launch_bounds__(1024) void cdc_prep_stats(
    const float* __restrict__ x, const float* __restrict__ Wc,
    const float* __restrict__ We, unsigned short* __restrict__ Bw,
    float* __restrict__ Wt, float* __restrict__ Wet,
    float* __restrict__ stats)
{
    const int blk = blockIdx.x;
    const int tid = threadIdx.x;
    if (blk < 512) {
        __shared__ float rT[16], rD[16], rR0[4], rR255[4], rC0[4], rC255[4], rCorn[4];
        const int j    = tid & 255;
        const int seg  = tid >> 8;      // uniform per wave
        const int w    = tid >> 6;
        const int lane = tid & 63;
        const float* p = x + (size_t)blk * 65536 + j;

        const int r0 = seg << 6;
        float colsum = 0.f, D = 0.f;
        float xm = (r0 == 0) ? 0.f : p[(size_t)(r0 - 1) * 256];
        float xc = p[(size_t)r0 * 256];
        const float x_first = xc;
        float x_last = 0.f;
        #pragma unroll 8
        for (int r = r0; r < r0 + 64; ++r) {
            float xp = (r + 1 < 256) ? p[(size_t)(r + 1) * 256] : 0.f;
            colsum += xc;
            D += fabsf(xm - xp);
            if (r == r0 + 63) x_last = xc;
            xm = xc; xc = xp;
        }

        float ts = wsum64(colsum);
        float ds = wsum64(D);
        if (lane == 0) { rT[w] = ts; rD[w] = ds; }
        if (seg == 0) {
            float fs = wsum64(x_first);
            if (lane == 0) rR0[w] = fs;
        } else if (seg == 3) {
            float fs = wsum64(x_last);
            if (lane == 0) rR255[w & 3] = fs;
        }
        if (j == 0) {
            rC0[seg] = colsum;
            if (seg == 0) rCorn[0] = x_first;        // x[0][0]
            if (seg == 3) rCorn[2] = x_last;         // x[255][0]
        }
        if (j == 255) {
            rC255[seg] = colsum;
            if (seg == 0) rCorn[1] = x_first;        // x[0][255]
            if (seg == 3) rCorn[3] = x_last;         // x[255][255]
        }
        __syncthreads();
        if (tid == 0) {
            float T = 0.f, Dt = 0.f;
            #pragma unroll
            for (int i = 0; i < 16; ++i) { T += rT[i]; Dt += rD[i]; }
            float* st = stats + (size_t)blk * 10;
            st[0] = T;
            st[1] = rR0[0] + rR0[1] + rR0[2] + rR0[3];
            st[2] = rR255[0] + rR255[1] + rR255[2] + rR255[3];
            st[3] = rC0[0] + rC0[1] + rC0[2] + rC0[3];
            st[4] = rC255[0] + rC255[1] + rC255[2] + rC255[3];
            st[5] = rCorn[0]; st[6] = rCorn[1]; st[7] = rCorn[2]; st[8] = rCorn[3];
            st[9] = Dt;
        }
    } else if (blk < 560) {
        int idx = (blk - 512) * 1024 + tid;
        if (idx >= 2 * 64 * 384) return;
        int k = idx % 384;
        int n = (idx / 384) & 63;
        int chunk = idx / 24576;
        int c0 = chunk << 5;
        float v = 0.f;
        if (k < 288) {
            int tap = k >> 5, cl = k & 31;
            v = THETA * Wc[n * 576 + (c0 + cl) * 9 + tap];
        } else if (k < 320) {
            int cl = k - 288;
            v = (1.0f - THETA) * We[n * 64 + c0 + cl];
        }
        Bw[idx] = f2bu(v);
    } else {
        int idx = (blk - 560) * 1024 + tid;
        if (idx < 36864) {
            int k = idx >> 6, o = idx & 63;           // k = c*9+tap
            Wt[idx] = Wc[o * 576 + k];
        } else if (idx < 40960) {
            int e = idx - 36864;
            int c = e >> 6, o = e & 63;
            Wet[e] = We[o * 64 + c];
        }
    }
}

// Main: per-block SE-attn prologue (closed-form pooled from stats, redundant
// per batch, coalesced via Wt/Wet), then implicit-GEMM conv+edge via
// 16x16x32 bf16 MFMA, attn applied at the final non-temporal write.
// No blockIdx swizzle (R2's batch-per-XCD remap caused 2.7x write
// amplification: concurrent dirty 64B-segment footprint exceeded L2).
// nt stores bypass L2 entirely -> no partial-line eviction hazard.
// LDS 31.9 KB, VGPR<=102 -> 5 blocks/CU.
__global__ __launch_bounds__(256, 5) void cdc_main_kernel(
    const float* __restrict__ x, const unsigned short* __restrict__ Bw,
    const float* __restrict__ stats, const float* __restrict__ Wt,
    const float* __restrict__ Wet, const float* __restrict__ bc,
    const float* __restrict__ W1, const float* __restrict__ b1,
    const float* __restrict__ W2, const float* __restrict__ b2,
    float* __restrict__ out)
{
    __shared__ unsigned short xs[18 * 22 * 40];   // 31680 B
    __shared__ float attn_sh[64];

    const int tid  = threadIdx.x;
    const int lane = tid & 63;
    const int w    = tid >> 6;
    const int m    = lane & 15;   // A: pixel-in-frag (img col); B/D: oc-in-frag
    const int q    = lane >> 4;   // k-subchunk quad

    const int b    = blockIdx.x >> 8;
    const int t    = blockIdx.x & 255;
    const int trow = ((t >> 4) & 15) << 4;
    const int tcol = (t & 15) << 4;

    // ---- SE attention prologue (aliases xs; finished before staging) ----
    {
        float* fst = (float*)xs;            // [64][10] this batch's stats
        float* pl  = fst + 640;             // pooled[64]
        float* hbv = fst + 704;             // h[8]
        for (int i = tid; i < 640; i += 256) fst[i] = stats[b * 640 + i];
        __syncthreads();
        if (tid < 64) {
            const int o = tid;
            float cs = 0.f, es = 0.f;
            for (int c = 0; c < 64; ++c) {
                const float* st = fst + c * 10;     // uniform addr -> broadcast
                const float T = st[0];
                const float Rex0 = st[2], Rex2 = st[1];   // ky=0:R255, ky=2:R0
                const float Cex0 = st[4], Cex2 = st[3];   // kx=0:C255, kx=2:C0
                const float s0 = T - Rex0 - Cex0 + st[8];
                const float s1 = T - Rex0;
                const float s2 = T - Rex0 - Cex2 + st[7];
                const float s3 = T - Cex0;
                const float s4 = T;
                const float s5 = T - Cex2;
                const float s6 = T - Rex2 - Cex0 + st[6];
                const float s7 = T - Rex2;
                const float s8 = T - Rex2 - Cex2 + st[5];
                const float* wp = Wt + (c * 9) * 64 + o;  // coalesced over o
                cs += wp[0]     * s0;
                cs += wp[64]    * s1;
                cs += wp[128]   * s2;
                cs += wp[192]   * s3;
                cs += wp[256]   * s4;
                cs += wp[320]   * s5;
                cs += wp[384]   * s6;
                cs += wp[448]   * s7;
                cs += wp[512]   * s8;
                es += Wet[c * 64 + o] * st[9];
            }
            pl[o] = THETA * (cs * (1.f / 65536.f) + bc[o])
                  + (1.0f - THETA) * (es * (1.f / 65536.f));
        }
        __syncthreads();
        if (tid < 8) {
            float s = b1[tid];
            for (int o = 0; o < 64; ++o) s += W1[tid * 64 + o] * pl[o];
            hbv[tid] = fmaxf(s, 0.f);
        }
        __syncthreads();
        if (tid < 64) {
            float z = b2[tid];
            #pragma unroll
            for (int r = 0; r < 8; ++r) z += W2[tid * 8 + r] * hbv[r];
            attn_sh[tid] = 1.0f / (1.0f + expf(-z));
        }
        // chunk loop's leading __syncthreads() orders these reads/writes
        // before staging overwrites xs.
    }

    const unsigned short* Bl = Bw + m * 384 + q * 8;   // per-lane weight base

    floatx4 acc[4][4];   // [mf][nf]; D: col=lane&15 (oc), row=q*4+reg (img col)
    #pragma unroll
    for (int nf = 0; nf < 4; ++nf) {
        float bias = THETA * bc[nf * 16 + m];
        #pragma unroll
        for (int mf = 0; mf < 4; ++mf)
            acc[mf][nf] = (floatx4){bias, bias, bias, bias};
    }

    for (int chunk = 0; chunk < 2; ++chunk) {
        const int c0 = chunk << 5;
        const unsigned short* Bc = Bl + chunk * 24576;
        __syncthreads();
        // ---- stage x chunk: 4x4 (col x c) transpose blocks, f32->bf16 ----
        for (int bi = tid; bi < 720; bi += 256) {
            const int cgrp = bi / 90;           // 0..7 (4 c each)
            const int rem  = bi - cgrp * 90;
            const int row  = rem / 5;           // 0..17 (halo rows)
            const int cg   = rem - row * 5;     // 0..4  (4 cols each)
            const int gr   = trow + row - 1;
            const int gc0  = tcol + (cg << 2) - 1;
            float v[4][4];
            const bool rok = (unsigned)gr < 256u;
            const float* xb = x + (((size_t)(b * 64 + c0 + cgrp * 4)) * 256 +
                                   (rok ? gr : 0)) * 256;
            if (rok && gc0 >= 0 && gc0 + 3 < 256) {
                #pragma unroll
                for (int i = 0; i < 4; ++i) {
                    float4 tv = *(const float4*)(xb + (size_t)i * 65536 + gc0);
                    v[i][0] = tv.x; v[i][1] = tv.y; v[i][2] = tv.z; v[i][3] = tv.w;
                }
            } else {
                #pragma unroll
                for (int i = 0; i < 4; ++i)
                    #pragma unroll
                    for (int e = 0; e < 4; ++e) {
                        int gc = gc0 + e;
                        v[i][e] = (rok && (unsigned)gc < 256u)
                                  ? xb[(size_t)i * 65536 + gc] : 0.f;
                    }
            }
            unsigned short* dst = &xs[(row * 22 + (cg << 2)) * 40 + (cgrp << 2)];
            #pragma unroll
            for (int e = 0; e < 4; ++e) {
                unsigned long long d =
                      (unsigned long long)f2bu(v[0][e])
                    | ((unsigned long long)f2bu(v[1][e]) << 16)
                    | ((unsigned long long)f2bu(v[2][e]) << 32)
                    | ((unsigned long long)f2bu(v[3][e]) << 48);
                *(unsigned long long*)(dst + e * 40) = d;
            }
        }
        __syncthreads();

        // ---- 9 conv ksteps; B-frags straight from global (L2-hot) ----
        #pragma unroll
        for (int tap = 0; tap < 9; ++tap) {
            const int dy = tap / 3, dx = tap % 3;
            short8 bf[4];
            #pragma unroll
            for (int nf = 0; nf < 4; ++nf)
                bf[nf] = *(const short8*)&Bc[nf * 6144 + tap * 32];
            #pragma unroll
            for (int mf = 0; mf < 4; ++mf) {
                const short8 af = *(const short8*)
                    &xs[((w * 4 + mf + dy) * 22 + (m + dx)) * 40 + q * 8];
                #pragma unroll
                for (int nf = 0; nf < 4; ++nf)
                    acc[mf][nf] = __builtin_amdgcn_mfma_f32_16x16x32_bf16(
                        af, bf[nf], acc[mf][nf], 0, 0, 0);
            }
        }
        // ---- edge kstep: A = |x(r-1) - x(r+1)| over 32 channels ----
        {
            short8 bf[4];
            #pragma unroll
            for (int nf = 0; nf < 4; ++nf)
                bf[nf] = *(const short8*)&Bc[nf * 6144 + 288];
            #pragma unroll
            for (int mf = 0; mf < 4; ++mf) {
                const short8 a0 = *(const short8*)
                    &xs[((w * 4 + mf) * 22 + m + 1) * 40 + q * 8];
                const short8 a1 = *(const short8*)
                    &xs[((w * 4 + mf + 2) * 22 + m + 1) * 40 + q * 8];
                short8 af;
                #pragma unroll
                for (int jj = 0; jj < 8; ++jj)
                    af[jj] = (short)f2bu(fabsf(
                        b2f((unsigned short)a0[jj]) - b2f((unsigned short)a1[jj])));
                #pragma unroll
                for (int nf = 0; nf < 4; ++nf)
                    acc[mf][nf] = __builtin_amdgcn_mfma_f32_16x16x32_bf16(
                        af, bf[nf], acc[mf][nf], 0, 0, 0);
            }
        }
    }

    // ---- apply attention, non-temporal final write (out never re-read) ----
    float av[4];
    #pragma unroll
    for (int nf = 0; nf < 4; ++nf) av[nf] = attn_sh[nf * 16 + m];
    #pragma unroll
    for (int mf = 0; mf < 4; ++mf) {
        const int y = trow + w * 4 + mf;
        #pragma unroll
        for (int nf = 0; nf < 4; ++nf) {
            const int oc = nf * 16 + m;
            size_t off = (((size_t)(b * 64 + oc)) * 256 + y) * 256 + tcol + q * 4;
            floatx4 val = acc[mf][nf] * av[nf];
            __builtin_nontemporal_store(val, (floatx4*)(out + off));
        }
    }
}

extern "C" void kernel_launch(void* const* d_in, const int* in_sizes, int n_in,
                              void* d_out, int out_size, void* d_ws, size_t ws_size,
                              hipStream_t stream)
{
    const float* x  = (const float*)d_in[0];
    const float* Wc = (const float*)d_in[1];
    const float* bc = (const float*)d_in[2];
    const float* We = (const float*)d_in[3];
    const float* W1 = (const float*)d_in[4];
    const float* b1 = (const float*)d_in[5];
    const float* W2 = (const float*)d_in[6];
    const float* b2 = (const float*)d_in[7];
    float* out  = (float*)d_out;

    float* stats = (float*)d_ws;                          // 5120 f32
    float* Wt    = stats + 5120;                          // 36864 f32
    float* Wet   = Wt + 36864;                            // 4096 f32
    unsigned short* Bw = (unsigned short*)(Wet + 4096);   // 49152 bf16

    cdc_prep_stats<<<600, 1024, 0, stream>>>(x, Wc, We, Bw, Wt, Wet, stats);
    cdc_main_kernel<<<2048, 256, 0, stream>>>(x, Bw, stats, Wt, Wet, bc,
                                              W1, b1, W2, b2, out);
}

// Round 4
// 459.652 us; speedup vs baseline: 1.6042x; 1.6042x over previous
//
#include <hip/hip_runtime.h>
#include <hip/hip_bf16.h>
#include <math.h>

#define THETA 0.7f

typedef short short8 __attribute__((ext_vector_type(8)));
typedef float floatx4 __attribute__((ext_vector_type(4)));

__device__ __forceinline__ unsigned short f2bu(float f) {
    return __builtin_bit_cast(unsigned short, __float2bfloat16(f));
}
__device__ __forceinline__ float b2f(unsigned short u) {
    unsigned v = ((unsigned)u) << 16;
    return __builtin_bit_cast(float, v);
}
__device__ __forceinline__ float wsum64(float v) {
    v += __shfl_xor(v, 32); v += __shfl_xor(v, 16); v += __shfl_xor(v, 8);
    v += __shfl_xor(v, 4);  v += __shfl_xor(v, 2);  v += __shfl_xor(v, 1);
    return v;
}

// Fused prep + stats, one launch (independent work, disjoint block ranges).
// Blocks 0..511   : per-(b,c)-plane stats (closed-form GAP inputs).
//   stats[plane*10 + {0:T,1:R0,2:R255,3:C0,4:C255,5:x00,6:x0_255,
//                     7:x255_0,8:x255_255,9:sum|x(r-1)-x(r+1)|}]
// Blocks 512..559 : Bw[2 chunks][64 n][384 k] bf16 fused weights.
// Blocks 560..599 : Wt[(c*9+tap)*64+o] = Wc[o*576+c*9+tap] (coalesced-read
//                   transpose) and Wet[c*64+o] = We[o*64+c].
__global__ __launch_bounds__(1024) void cdc_prep_stats(
    const float* __restrict__ x, const float* __restrict__ Wc,
    const float* __restrict__ We, unsigned short* __restrict__ Bw,
    float* __restrict__ Wt, float* __restrict__ Wet,
    float* __restrict__ stats)
{
    const int blk = blockIdx.x;
    const int tid = threadIdx.x;
    if (blk < 512) {
        __shared__ float rT[16], rD[16], rR0[4], rR255[4], rC0[4], rC255[4], rCorn[4];
        const int j    = tid & 255;
        const int seg  = tid >> 8;      // uniform per wave
        const int w    = tid >> 6;
        const int lane = tid & 63;
        const float* p = x + (size_t)blk * 65536 + j;

        const int r0 = seg << 6;
        float colsum = 0.f, D = 0.f;
        float xm = (r0 == 0) ? 0.f : p[(size_t)(r0 - 1) * 256];
        float xc = p[(size_t)r0 * 256];
        const float x_first = xc;
        float x_last = 0.f;
        #pragma unroll 8
        for (int r = r0; r < r0 + 64; ++r) {
            float xp = (r + 1 < 256) ? p[(size_t)(r + 1) * 256] : 0.f;
            colsum += xc;
            D += fabsf(xm - xp);
            if (r == r0 + 63) x_last = xc;
            xm = xc; xc = xp;
        }

        float ts = wsum64(colsum);
        float ds = wsum64(D);
        if (lane == 0) { rT[w] = ts; rD[w] = ds; }
        if (seg == 0) {
            float fs = wsum64(x_first);
            if (lane == 0) rR0[w] = fs;
        } else if (seg == 3) {
            float fs = wsum64(x_last);
            if (lane == 0) rR255[w & 3] = fs;
        }
        if (j == 0) {
            rC0[seg] = colsum;
            if (seg == 0) rCorn[0] = x_first;        // x[0][0]
            if (seg == 3) rCorn[2] = x_last;         // x[255][0]
        }
        if (j == 255) {
            rC255[seg] = colsum;
            if (seg == 0) rCorn[1] = x_first;        // x[0][255]
            if (seg == 3) rCorn[3] = x_last;         // x[255][255]
        }
        __syncthreads();
        if (tid == 0) {
            float T = 0.f, Dt = 0.f;
            #pragma unroll
            for (int i = 0; i < 16; ++i) { T += rT[i]; Dt += rD[i]; }
            float* st = stats + (size_t)blk * 10;
            st[0] = T;
            st[1] = rR0[0] + rR0[1] + rR0[2] + rR0[3];
            st[2] = rR255[0] + rR255[1] + rR255[2] + rR255[3];
            st[3] = rC0[0] + rC0[1] + rC0[2] + rC0[3];
            st[4] = rC255[0] + rC255[1] + rC255[2] + rC255[3];
            st[5] = rCorn[0]; st[6] = rCorn[1]; st[7] = rCorn[2]; st[8] = rCorn[3];
            st[9] = Dt;
        }
    } else if (blk < 560) {
        int idx = (blk - 512) * 1024 + tid;
        if (idx >= 2 * 64 * 384) return;
        int k = idx % 384;
        int n = (idx / 384) & 63;
        int chunk = idx / 24576;
        int c0 = chunk << 5;
        float v = 0.f;
        if (k < 288) {
            int tap = k >> 5, cl = k & 31;
            v = THETA * Wc[n * 576 + (c0 + cl) * 9 + tap];
        } else if (k < 320) {
            int cl = k - 288;
            v = (1.0f - THETA) * We[n * 64 + c0 + cl];
        }
        Bw[idx] = f2bu(v);
    } else {
        int idx = (blk - 560) * 1024 + tid;
        if (idx < 36864) {
            int k = idx >> 6, o = idx & 63;           // k = c*9+tap
            Wt[idx] = Wc[o * 576 + k];
        } else if (idx < 40960) {
            int e = idx - 36864;
            int c = e >> 6, o = e & 63;
            Wet[e] = We[o * 64 + c];
        }
    }
}

// Main: per-block SE-attn prologue (closed-form pooled from stats, redundant
// per batch, coalesced via Wt/Wet), then implicit-GEMM conv+edge via
// 16x16x32 bf16 MFMA, attn applied at the final write.
// __launch_bounds__(256,4): 128 VGPR/wave budget -> acc[4][4] (64 regs) fits
// with no spill (R3's (256,5) squeezed to 96 and spilled acc to scratch:
// FETCH 171->836 MB, WRITE 354->1378 MB, 3x slower).
// Plain stores, no blockIdx swizzle: sibling 64B half-lines come from
// consecutively-launched adjacent tiles and merge in L2 (R0: byte-exact
// 131.5 MB writes). R2's batch-per-XCD swizzle gave 2.7x write amplification.
__global__ __launch_bounds__(256, 4) void cdc_main_kernel(
    const float* __restrict__ x, const unsigned short* __restrict__ Bw,
    const float* __restrict__ stats, const float* __restrict__ Wt,
    const float* __restrict__ Wet, const float* __restrict__ bc,
    const float* __restrict__ W1, const float* __restrict__ b1,
    const float* __restrict__ W2, const float* __restrict__ b2,
    float* __restrict__ out)
{
    __shared__ unsigned short xs[18 * 22 * 40];   // 31680 B
    __shared__ float attn_sh[64];

    const int tid  = threadIdx.x;
    const int lane = tid & 63;
    const int w    = tid >> 6;
    const int m    = lane & 15;   // A: pixel-in-frag (img col); B/D: oc-in-frag
    const int q    = lane >> 4;   // k-subchunk quad

    const int b    = blockIdx.x >> 8;
    const int t    = blockIdx.x & 255;
    const int trow = ((t >> 4) & 15) << 4;
    const int tcol = (t & 15) << 4;

    // ---- SE attention prologue (aliases xs; finished before staging) ----
    {
        float* fst = (float*)xs;            // [64][10] this batch's stats
        float* pl  = fst + 640;             // pooled[64]
        float* hbv = fst + 704;             // h[8]
        for (int i = tid; i < 640; i += 256) fst[i] = stats[b * 640 + i];
        __syncthreads();
        if (tid < 64) {
            const int o = tid;
            float cs = 0.f, es = 0.f;
            for (int c = 0; c < 64; ++c) {
                const float* st = fst + c * 10;     // uniform addr -> broadcast
                const float T = st[0];
                const float Rex0 = st[2], Rex2 = st[1];   // ky=0:R255, ky=2:R0
                const float Cex0 = st[4], Cex2 = st[3];   // kx=0:C255, kx=2:C0
                const float s0 = T - Rex0 - Cex0 + st[8];
                const float s1 = T - Rex0;
                const float s2 = T - Rex0 - Cex2 + st[7];
                const float s3 = T - Cex0;
                const float s4 = T;
                const float s5 = T - Cex2;
                const float s6 = T - Rex2 - Cex0 + st[6];
                const float s7 = T - Rex2;
                const float s8 = T - Rex2 - Cex2 + st[5];
                const float* wp = Wt + (c * 9) * 64 + o;  // coalesced over o
                cs += wp[0]     * s0;
                cs += wp[64]    * s1;
                cs += wp[128]   * s2;
                cs += wp[192]   * s3;
                cs += wp[256]   * s4;
                cs += wp[320]   * s5;
                cs += wp[384]   * s6;
                cs += wp[448]   * s7;
                cs += wp[512]   * s8;
                es += Wet[c * 64 + o] * st[9];
            }
            pl[o] = THETA * (cs * (1.f / 65536.f) + bc[o])
                  + (1.0f - THETA) * (es * (1.f / 65536.f));
        }
        __syncthreads();
        if (tid < 8) {
            float s = b1[tid];
            for (int o = 0; o < 64; ++o) s += W1[tid * 64 + o] * pl[o];
            hbv[tid] = fmaxf(s, 0.f);
        }
        __syncthreads();
        if (tid < 64) {
            float z = b2[tid];
            #pragma unroll
            for (int r = 0; r < 8; ++r) z += W2[tid * 8 + r] * hbv[r];
            attn_sh[tid] = 1.0f / (1.0f + expf(-z));
        }
        // chunk loop's leading __syncthreads() orders these reads/writes
        // before staging overwrites xs.
    }

    const unsigned short* Bl = Bw + m * 384 + q * 8;   // per-lane weight base

    floatx4 acc[4][4];   // [mf][nf]; D: col=lane&15 (oc), row=q*4+reg (img col)
    #pragma unroll
    for (int nf = 0; nf < 4; ++nf) {
        float bias = THETA * bc[nf * 16 + m];
        #pragma unroll
        for (int mf = 0; mf < 4; ++mf)
            acc[mf][nf] = (floatx4){bias, bias, bias, bias};
    }

    for (int chunk = 0; chunk < 2; ++chunk) {
        const int c0 = chunk << 5;
        const unsigned short* Bc = Bl + chunk * 24576;
        __syncthreads();
        // ---- stage x chunk: 4x4 (col x c) transpose blocks, f32->bf16 ----
        for (int bi = tid; bi < 720; bi += 256) {
            const int cgrp = bi / 90;           // 0..7 (4 c each)
            const int rem  = bi - cgrp * 90;
            const int row  = rem / 5;           // 0..17 (halo rows)
            const int cg   = rem - row * 5;     // 0..4  (4 cols each)
            const int gr   = trow + row - 1;
            const int gc0  = tcol + (cg << 2) - 1;
            float v[4][4];
            const bool rok = (unsigned)gr < 256u;
            const float* xb = x + (((size_t)(b * 64 + c0 + cgrp * 4)) * 256 +
                                   (rok ? gr : 0)) * 256;
            if (rok && gc0 >= 0 && gc0 + 3 < 256) {
                #pragma unroll
                for (int i = 0; i < 4; ++i) {
                    float4 tv = *(const float4*)(xb + (size_t)i * 65536 + gc0);
                    v[i][0] = tv.x; v[i][1] = tv.y; v[i][2] = tv.z; v[i][3] = tv.w;
                }
            } else {
                #pragma unroll
                for (int i = 0; i < 4; ++i)
                    #pragma unroll
                    for (int e = 0; e < 4; ++e) {
                        int gc = gc0 + e;
                        v[i][e] = (rok && (unsigned)gc < 256u)
                                  ? xb[(size_t)i * 65536 + gc] : 0.f;
                    }
            }
            unsigned short* dst = &xs[(row * 22 + (cg << 2)) * 40 + (cgrp << 2)];
            #pragma unroll
            for (int e = 0; e < 4; ++e) {
                unsigned long long d =
                      (unsigned long long)f2bu(v[0][e])
                    | ((unsigned long long)f2bu(v[1][e]) << 16)
                    | ((unsigned long long)f2bu(v[2][e]) << 32)
                    | ((unsigned long long)f2bu(v[3][e]) << 48);
                *(unsigned long long*)(dst + e * 40) = d;
            }
        }
        __syncthreads();

        // ---- 9 conv ksteps; B-frags straight from global (L2-hot) ----
        #pragma unroll
        for (int tap = 0; tap < 9; ++tap) {
            const int dy = tap / 3, dx = tap % 3;
            short8 bf[4];
            #pragma unroll
            for (int nf = 0; nf < 4; ++nf)
                bf[nf] = *(const short8*)&Bc[nf * 6144 + tap * 32];
            #pragma unroll
            for (int mf = 0; mf < 4; ++mf) {
                const short8 af = *(const short8*)
                    &xs[((w * 4 + mf + dy) * 22 + (m + dx)) * 40 + q * 8];
                #pragma unroll
                for (int nf = 0; nf < 4; ++nf)
                    acc[mf][nf] = __builtin_amdgcn_mfma_f32_16x16x32_bf16(
                        af, bf[nf], acc[mf][nf], 0, 0, 0);
            }
        }
        // ---- edge kstep: A = |x(r-1) - x(r+1)| over 32 channels ----
        {
            short8 bf[4];
            #pragma unroll
            for (int nf = 0; nf < 4; ++nf)
                bf[nf] = *(const short8*)&Bc[nf * 6144 + 288];
            #pragma unroll
            for (int mf = 0; mf < 4; ++mf) {
                const short8 a0 = *(const short8*)
                    &xs[((w * 4 + mf) * 22 + m + 1) * 40 + q * 8];
                const short8 a1 = *(const short8*)
                    &xs[((w * 4 + mf + 2) * 22 + m + 1) * 40 + q * 8];
                short8 af;
                #pragma unroll
                for (int jj = 0; jj < 8; ++jj)
                    af[jj] = (short)f2bu(fabsf(
                        b2f((unsigned short)a0[jj]) - b2f((unsigned short)a1[jj])));
                #pragma unroll
                for (int nf = 0; nf < 4; ++nf)
                    acc[mf][nf] = __builtin_amdgcn_mfma_f32_16x16x32_bf16(
                        af, bf[nf], acc[mf][nf], 0, 0, 0);
            }
        }
    }

    // ---- apply attention, write final output ----
    float av[4];
    #pragma unroll
    for (int nf = 0; nf < 4; ++nf) av[nf] = attn_sh[nf * 16 + m];
    #pragma unroll
    for (int mf = 0; mf < 4; ++mf) {
        const int y = trow + w * 4 + mf;
        #pragma unroll
        for (int nf = 0; nf < 4; ++nf) {
            const int oc = nf * 16 + m;
            size_t off = (((size_t)(b * 64 + oc)) * 256 + y) * 256 + tcol + q * 4;
            float4 val = make_float4(acc[mf][nf][0] * av[nf],
                                     acc[mf][nf][1] * av[nf],
                                     acc[mf][nf][2] * av[nf],
                                     acc[mf][nf][3] * av[nf]);
            *(float4*)(out + off) = val;
        }
    }
}

extern "C" void kernel_launch(void* const* d_in, const int* in_sizes, int n_in,
                              void* d_out, int out_size, void* d_ws, size_t ws_size,
                              hipStream_t stream)
{
    const float* x  = (const float*)d_in[0];
    const float* Wc = (const float*)d_in[1];
    const float* bc = (const float*)d_in[2];
    const float* We = (const float*)d_in[3];
    const float* W1 = (const float*)d_in[4];
    const float* b1 = (const float*)d_in[5];
    const float* W2 = (const float*)d_in[6];
    const float* b2 = (const float*)d_in[7];
    float* out  = (float*)d_out;

    float* stats = (float*)d_ws;                          // 5120 f32
    float* Wt    = stats + 5120;                          // 36864 f32
    float* Wet   = Wt + 36864;                            // 4096 f32
    unsigned short* Bw = (unsigned short*)(Wet + 4096);   // 49152 bf16

    cdc_prep_stats<<<600, 1024, 0, stream>>>(x, Wc, We, Bw, Wt, Wet, stats);
    cdc_main_kernel<<<2048, 256, 0, stream>>>(x, Bw, stats, Wt, Wet, bc,
                                              W1, b1, W2, b2, out);
}

// Round 5
// 384.200 us; speedup vs baseline: 1.9192x; 1.1964x over previous
//
#include <hip/hip_runtime.h>
#include <hip/hip_bf16.h>
#include <math.h>

#define THETA 0.7f

typedef short short8 __attribute__((ext_vector_type(8)));
typedef float floatx4 __attribute__((ext_vector_type(4)));

__device__ __forceinline__ unsigned short f2bu(float f) {
    return __builtin_bit_cast(unsigned short, __float2bfloat16(f));
}
__device__ __forceinline__ float b2f(unsigned short u) {
    unsigned v = ((unsigned)u) << 16;
    return __builtin_bit_cast(float, v);
}
__device__ __forceinline__ float wsum64(float v) {
    v += __shfl_xor(v, 32); v += __shfl_xor(v, 16); v += __shfl_xor(v, 8);
    v += __shfl_xor(v, 4);  v += __shfl_xor(v, 2);  v += __shfl_xor(v, 1);
    return v;
}

// Fused prep + stats, one launch (independent work, disjoint block ranges).
// Blocks 0..511   : per-(b,c)-plane stats (closed-form GAP inputs).
//   stats[plane*10 + {0:T,1:R0,2:R255,3:C0,4:C255,5:x00,6:x0_255,
//                     7:x255_0,8:x255_255,9:sum|x(r-1)-x(r+1)|}]
//   float4 row loads: wave = one 16-row segment, lane = 4-col group ->
//   each load instruction covers one full 1KB row (16B/lane, coalesced).
// Blocks 512..559 : Bw[2 chunks][64 n][384 k] bf16 fused weights.
// Blocks 560..599 : Wt[(c*9+tap)*64+o], Wet[c*64+o] transposes.
__global__ __launch_bounds__(1024) void cdc_prep_stats(
    const float* __restrict__ x, const float* __restrict__ Wc,
    const float* __restrict__ We, unsigned short* __restrict__ Bw,
    float* __restrict__ Wt, float* __restrict__ Wet,
    float* __restrict__ stats)
{
    const int blk = blockIdx.x;
    const int tid = threadIdx.x;
    if (blk < 512) {
        __shared__ float rT[16], rD[16], rC0[16], rC255[16], rEx[6];
        const int w    = tid >> 6;      // wave = seg (16 rows)
        const int lane = tid & 63;      // 4-col group
        const floatx4* p4 = (const floatx4*)(x + (size_t)blk * 65536) + lane;

        const int r0 = w << 4;
        const floatx4 z = {0.f, 0.f, 0.f, 0.f};
        floatx4 xm = (r0 == 0) ? z : p4[(r0 - 1) * 64];
        floatx4 xc = p4[r0 * 64];
        const floatx4 first = xc;
        floatx4 cs = z, Dv = z, last = z;
        #pragma unroll
        for (int r = r0; r < r0 + 16; ++r) {
            floatx4 xp = (r + 1 < 256) ? p4[(r + 1) * 64] : z;
            cs += xc;
            Dv.x += fabsf(xm.x - xp.x);
            Dv.y += fabsf(xm.y - xp.y);
            Dv.z += fabsf(xm.z - xp.z);
            Dv.w += fabsf(xm.w - xp.w);
            if (r == r0 + 15) last = xc;
            xm = xc; xc = xp;
        }

        float ts = wsum64(cs.x + cs.y + cs.z + cs.w);
        float ds = wsum64(Dv.x + Dv.y + Dv.z + Dv.w);
        float c255 = __shfl(cs.w, 63);
        if (w == 0) {
            float fs = wsum64(first.x + first.y + first.z + first.w);
            float x0_255 = __shfl(first.w, 63);
            if (lane == 0) { rEx[0] = fs; rEx[2] = first.x; rEx[3] = x0_255; }
        } else if (w == 15) {
            float ls = wsum64(last.x + last.y + last.z + last.w);
            float x255_255 = __shfl(last.w, 63);
            if (lane == 0) { rEx[1] = ls; rEx[4] = last.x; rEx[5] = x255_255; }
        }
        if (lane == 0) { rT[w] = ts; rD[w] = ds; rC0[w] = cs.x; rC255[w] = c255; }
        __syncthreads();
        if (tid == 0) {
            float T = 0.f, Dt = 0.f, C0 = 0.f, C255 = 0.f;
            #pragma unroll
            for (int i = 0; i < 16; ++i) {
                T += rT[i]; Dt += rD[i]; C0 += rC0[i]; C255 += rC255[i];
            }
            float* st = stats + (size_t)blk * 10;
            st[0] = T;
            st[1] = rEx[0];   // R0
            st[2] = rEx[1];   // R255
            st[3] = C0;
            st[4] = C255;
            st[5] = rEx[2];   // x00
            st[6] = rEx[3];   // x0_255
            st[7] = rEx[4];   // x255_0
            st[8] = rEx[5];   // x255_255
            st[9] = Dt;
        }
    } else if (blk < 560) {
        int idx = (blk - 512) * 1024 + tid;
        if (idx >= 2 * 64 * 384) return;
        int k = idx % 384;
        int n = (idx / 384) & 63;
        int chunk = idx / 24576;
        int c0 = chunk << 5;
        float v = 0.f;
        if (k < 288) {
            int tap = k >> 5, cl = k & 31;
            v = THETA * Wc[n * 576 + (c0 + cl) * 9 + tap];
        } else if (k < 320) {
            int cl = k - 288;
            v = (1.0f - THETA) * We[n * 64 + c0 + cl];
        }
        Bw[idx] = f2bu(v);
    } else {
        int idx = (blk - 560) * 1024 + tid;
        if (idx < 36864) {
            int k = idx >> 6, o = idx & 63;           // k = c*9+tap
            Wt[idx] = Wc[o * 576 + k];
        } else if (idx < 40960) {
            int e = idx - 36864;
            int c = e >> 6, o = e & 63;
            Wet[e] = We[o * 64 + c];
        }
    }
}

// Main: SE-attn prologue (closed-form pooled from stats) + implicit-GEMM
// conv+edge via 16x16x32 bf16 MFMA, attn applied at the final write.
//
// TILE = 32 cols x 8 rows (was 16x16). Per (oc,y) each WAVE writes the full
// 128 B line [tcol, tcol+32) via two adjacent float4 stores -> no cross-block
// half-line merging needed. R4 proved partial 64 B line writes at 4 blocks/CU
// cause RFO + double-writeback (FETCH 366 MB, WRITE 374 MB vs 134 ideal).
// Wave w: rows 2w..2w+1, both 16-col groups; mf = (row-in-pair)*2 + colgroup.
// Batch-per-XCD swizzle (2048%8==0) for x-fetch L2 locality — safe now that
// writes are self-contained (R4 showed write-amp occurs without swizzle too).
// LDS 28.8 KB + attn_sh; __launch_bounds__(256,4): VGPR 64 + AGPR acc, no
// spill (R3's (256,5) spilled: 3x slower).
__global__ __launch_bounds__(256, 4) void cdc_main_kernel(
    const float* __restrict__ x, const unsigned short* __restrict__ Bw,
    const float* __restrict__ stats, const float* __restrict__ Wt,
    const float* __restrict__ Wet, const float* __restrict__ bc,
    const float* __restrict__ W1, const float* __restrict__ b1,
    const float* __restrict__ W2, const float* __restrict__ b2,
    float* __restrict__ out)
{
    __shared__ unsigned short xs[10 * 36 * 40];   // 28800 B
    __shared__ float attn_sh[64];

    const int tid  = threadIdx.x;
    const int lane = tid & 63;
    const int w    = tid >> 6;
    const int m    = lane & 15;   // A: pixel-in-frag (img col); B/D: oc-in-frag
    const int q    = lane >> 4;   // k-subchunk quad

    int wg = (int)blockIdx.x;
    wg = ((wg & 7) << 8) | (wg >> 3);   // XCD-contiguous, bijective (batch/XCD)
    const int b    = wg >> 8;
    const int t    = wg & 255;
    const int trow = (t >> 3) << 3;     // 32 row-tiles of 8
    const int tcol = (t & 7) << 5;      // 8 col-tiles of 32

    // ---- SE attention prologue (aliases xs; finished before staging) ----
    {
        float* fst = (float*)xs;            // [64][10] this batch's stats
        float* pl  = fst + 640;             // pooled[64]
        float* hbv = fst + 704;             // h[8]
        for (int i = tid; i < 640; i += 256) fst[i] = stats[b * 640 + i];
        __syncthreads();
        if (tid < 64) {
            const int o = tid;
            float cs = 0.f, es = 0.f;
            for (int c = 0; c < 64; ++c) {
                const float* st = fst + c * 10;     // uniform addr -> broadcast
                const float T = st[0];
                const float Rex0 = st[2], Rex2 = st[1];   // ky=0:R255, ky=2:R0
                const float Cex0 = st[4], Cex2 = st[3];   // kx=0:C255, kx=2:C0
                const float s0 = T - Rex0 - Cex0 + st[8];
                const float s1 = T - Rex0;
                const float s2 = T - Rex0 - Cex2 + st[7];
                const float s3 = T - Cex0;
                const float s4 = T;
                const float s5 = T - Cex2;
                const float s6 = T - Rex2 - Cex0 + st[6];
                const float s7 = T - Rex2;
                const float s8 = T - Rex2 - Cex2 + st[5];
                const float* wp = Wt + (c * 9) * 64 + o;  // coalesced over o
                cs += wp[0]   * s0;
                cs += wp[64]  * s1;
                cs += wp[128] * s2;
                cs += wp[192] * s3;
                cs += wp[256] * s4;
                cs += wp[320] * s5;
                cs += wp[384] * s6;
                cs += wp[448] * s7;
                cs += wp[512] * s8;
                es += Wet[c * 64 + o] * st[9];
            }
            pl[o] = THETA * (cs * (1.f / 65536.f) + bc[o])
                  + (1.0f - THETA) * (es * (1.f / 65536.f));
        }
        __syncthreads();
        if (tid < 8) {
            float s = b1[tid];
            for (int o = 0; o < 64; ++o) s += W1[tid * 64 + o] * pl[o];
            hbv[tid] = fmaxf(s, 0.f);
        }
        __syncthreads();
        if (tid < 64) {
            float z = b2[tid];
            #pragma unroll
            for (int r = 0; r < 8; ++r) z += W2[tid * 8 + r] * hbv[r];
            attn_sh[tid] = 1.0f / (1.0f + expf(-z));
        }
        // chunk loop's leading __syncthreads() orders these before staging
        // overwrites xs.
    }

    const unsigned short* Bl = Bw + m * 384 + q * 8;   // per-lane weight base

    floatx4 acc[4][4];   // [mf][nf]; mf = (row-in-pair)*2+cg
    #pragma unroll
    for (int nf = 0; nf < 4; ++nf) {
        float bias = THETA * bc[nf * 16 + m];
        #pragma unroll
        for (int mf = 0; mf < 4; ++mf)
            acc[mf][nf] = (floatx4){bias, bias, bias, bias};
    }

    for (int chunk = 0; chunk < 2; ++chunk) {
        const int c0 = chunk << 5;
        const unsigned short* Bc = Bl + chunk * 24576;
        __syncthreads();
        // ---- stage x chunk: rows trow-1..trow+8, cols tcol-1..tcol+34 ----
        // 720 items: 8 ch-groups x 10 rows x 9 col-groups (4 cols each)
        for (int bi = tid; bi < 720; bi += 256) {
            const int cgrp = bi / 90;           // 0..7 (4 c each)
            const int rem  = bi - cgrp * 90;
            const int row  = rem / 9;           // 0..9  (halo rows)
            const int cg   = rem - row * 9;     // 0..8  (4 cols each)
            const int gr   = trow + row - 1;
            const int gc0  = tcol + (cg << 2) - 1;
            float v[4][4];
            const bool rok = (unsigned)gr < 256u;
            const float* xb = x + (((size_t)(b * 64 + c0 + cgrp * 4)) * 256 +
                                   (rok ? gr : 0)) * 256;
            if (rok && gc0 >= 0 && gc0 + 3 < 256) {
                #pragma unroll
                for (int i = 0; i < 4; ++i) {
                    float4 tv = *(const float4*)(xb + (size_t)i * 65536 + gc0);
                    v[i][0] = tv.x; v[i][1] = tv.y; v[i][2] = tv.z; v[i][3] = tv.w;
                }
            } else {
                #pragma unroll
                for (int i = 0; i < 4; ++i)
                    #pragma unroll
                    for (int e = 0; e < 4; ++e) {
                        int gc = gc0 + e;
                        v[i][e] = (rok && (unsigned)gc < 256u)
                                  ? xb[(size_t)i * 65536 + gc] : 0.f;
                    }
            }
            unsigned short* dst = &xs[(row * 36 + (cg << 2)) * 40 + (cgrp << 2)];
            #pragma unroll
            for (int e = 0; e < 4; ++e) {
                unsigned long long d =
                      (unsigned long long)f2bu(v[0][e])
                    | ((unsigned long long)f2bu(v[1][e]) << 16)
                    | ((unsigned long long)f2bu(v[2][e]) << 32)
                    | ((unsigned long long)f2bu(v[3][e]) << 48);
                *(unsigned long long*)(dst + e * 40) = d;
            }
        }
        __syncthreads();

        // ---- 9 conv ksteps; B-frags straight from global (L2-hot) ----
        #pragma unroll
        for (int tap = 0; tap < 9; ++tap) {
            const int dy = tap / 3, dx = tap % 3;
            short8 bf[4];
            #pragma unroll
            for (int nf = 0; nf < 4; ++nf)
                bf[nf] = *(const short8*)&Bc[nf * 6144 + tap * 32];
            #pragma unroll
            for (int mf = 0; mf < 4; ++mf) {
                const int ri = mf >> 1, cg = mf & 1;
                const short8 af = *(const short8*)
                    &xs[((2 * w + ri + dy) * 36 + (cg * 16 + m + dx)) * 40 + q * 8];
                #pragma unroll
                for (int nf = 0; nf < 4; ++nf)
                    acc[mf][nf] = __builtin_amdgcn_mfma_f32_16x16x32_bf16(
                        af, bf[nf], acc[mf][nf], 0, 0, 0);
            }
        }
        // ---- edge kstep: A = |x(r-1) - x(r+1)| over 32 channels ----
        {
            short8 bf[4];
            #pragma unroll
            for (int nf = 0; nf < 4; ++nf)
                bf[nf] = *(const short8*)&Bc[nf * 6144 + 288];
            #pragma unroll
            for (int mf = 0; mf < 4; ++mf) {
                const int ri = mf >> 1, cg = mf & 1;
                const short8 a0 = *(const short8*)
                    &xs[((2 * w + ri) * 36 + cg * 16 + m + 1) * 40 + q * 8];
                const short8 a1 = *(const short8*)
                    &xs[((2 * w + ri + 2) * 36 + cg * 16 + m + 1) * 40 + q * 8];
                short8 af;
                #pragma unroll
                for (int jj = 0; jj < 8; ++jj)
                    af[jj] = (short)f2bu(fabsf(
                        b2f((unsigned short)a0[jj]) - b2f((unsigned short)a1[jj])));
                #pragma unroll
                for (int nf = 0; nf < 4; ++nf)
                    acc[mf][nf] = __builtin_amdgcn_mfma_f32_16x16x32_bf16(
                        af, bf[nf], acc[mf][nf], 0, 0, 0);
            }
        }
    }

    // ---- apply attention, write final output ----
    // Per (oc,y): cg=0 and cg=1 stores from the SAME wave complete the full
    // 128 B line [tcol, tcol+32) back-to-back.
    float av[4];
    #pragma unroll
    for (int nf = 0; nf < 4; ++nf) av[nf] = attn_sh[nf * 16 + m];
    #pragma unroll
    for (int ri = 0; ri < 2; ++ri) {
        const int y = trow + 2 * w + ri;
        #pragma unroll
        for (int nf = 0; nf < 4; ++nf) {
            const int oc = nf * 16 + m;
            size_t base = (((size_t)(b * 64 + oc)) * 256 + y) * 256 + tcol + q * 4;
            #pragma unroll
            for (int cg = 0; cg < 2; ++cg) {
                const floatx4 a = acc[ri * 2 + cg][nf];
                float4 val = make_float4(a[0] * av[nf], a[1] * av[nf],
                                         a[2] * av[nf], a[3] * av[nf]);
                *(float4*)(out + base + cg * 16) = val;
            }
        }
    }
}

extern "C" void kernel_launch(void* const* d_in, const int* in_sizes, int n_in,
                              void* d_out, int out_size, void* d_ws, size_t ws_size,
                              hipStream_t stream)
{
    const float* x  = (const float*)d_in[0];
    const float* Wc = (const float*)d_in[1];
    const float* bc = (const float*)d_in[2];
    const float* We = (const float*)d_in[3];
    const float* W1 = (const float*)d_in[4];
    const float* b1 = (const float*)d_in[5];
    const float* W2 = (const float*)d_in[6];
    const float* b2 = (const float*)d_in[7];
    float* out  = (float*)d_out;

    float* stats = (float*)d_ws;                          // 5120 f32
    float* Wt    = stats + 5120;                          // 36864 f32
    float* Wet   = Wt + 36864;                            // 4096 f32
    unsigned short* Bw = (unsigned short*)(Wet + 4096);   // 49152 bf16

    cdc_prep_stats<<<600, 1024, 0, stream>>>(x, Wc, We, Bw, Wt, Wet, stats);
    cdc_main_kernel<<<2048, 256, 0, stream>>>(x, Bw, stats, Wt, Wet, bc,
                                              W1, b1, W2, b2, out);
}